// Round 13
// baseline (528.847 us; speedup 1.0000x reference)
//
#include <hip/hip_runtime.h>
#include <math.h>

// Split design (R11 post-mortem: fused kernel stuck at 224us, hbm 2.5 TB/s,
// occupancy-insensitive -> phase-1 MLP starvation, not occupancy/BW).
// K1: per block = 8 tokens. H = W_phi.hs + norms, double-buffered hs prefetch
//     (hA/hB) so next iter's HBM loads are in flight during FMAs.
//     Ends with sinkhorn+gates, writes 24 floats/token to d_ws.
// K2: per block = 1 token. Pure streaming recombination: reads gates (96B) +
//     hs (32KB, expected L3-hot), writes out (32KB). Tiny state -> high occ.

__global__ __launch_bounds__(256)
void mhc_gates(const float* __restrict__ hs,
               const float* __restrict__ Wphi,
               const float* __restrict__ av,
               const float* __restrict__ bv,
               float* __restrict__ gates)   // [tokens][24]: pre[4] post[4] res[16]
{
    const int tid  = threadIdx.x;
    const int wave = tid >> 6;
    const int lane = tid & 63;
    const long long t0 = (long long)blockIdx.x * 8;

    __shared__ float Hlds[8][25];

    const int obase = wave * 6;
    const float4* hs4 = reinterpret_cast<const float4*>(hs + t0 * 8192);
    const float4* W4  = reinterpret_cast<const float4*>(Wphi) + (size_t)obase * 2048;

    float acc[8][6];
    float accN[8];
#pragma unroll
    for (int t = 0; t < 8; ++t) {
        accN[t] = 0.f;
#pragma unroll
        for (int o = 0; o < 6; ++o) acc[t][o] = 0.f;
    }

    float4 hA[8], hB[8];
#pragma unroll
    for (int t = 0; t < 8; ++t) hA[t] = hs4[t * 2048 + lane];

    // FMA on buffer `hb` at float4 index k4 (and norm on wave 0)
    auto fma_blk = [&](const float4* hb, int k4) {
#pragma unroll
        for (int o = 0; o < 6; ++o) {
            const float4 w = W4[o * 2048 + k4];
#pragma unroll
            for (int t = 0; t < 8; ++t)
                acc[t][o] += w.x * hb[t].x + w.y * hb[t].y
                           + w.z * hb[t].z + w.w * hb[t].w;
        }
        if (wave == 0) {
#pragma unroll
            for (int t = 0; t < 8; ++t)
                accN[t] += hb[t].x * hb[t].x + hb[t].y * hb[t].y
                         + hb[t].z * hb[t].z + hb[t].w * hb[t].w;
        }
    };

    for (int i = 0; i < 32; i += 2) {
        // prefetch iter i+1 into hB while computing on hA
        {
            const int kn = lane + ((i + 1) << 6);
#pragma unroll
            for (int t = 0; t < 8; ++t) hB[t] = hs4[t * 2048 + kn];
        }
        fma_blk(hA, lane + (i << 6));
        // prefetch iter i+2 into hA while computing on hB
        if (i + 2 < 32) {
            const int kn = lane + ((i + 2) << 6);
#pragma unroll
            for (int t = 0; t < 8; ++t) hA[t] = hs4[t * 2048 + kn];
        }
        fma_blk(hB, lane + ((i + 1) << 6));
    }

    // butterfly reduce across 64 lanes, lane 0 writes LDS
#pragma unroll
    for (int t = 0; t < 8; ++t) {
#pragma unroll
        for (int o = 0; o < 6; ++o) {
            float v = acc[t][o];
            v += __shfl_xor(v, 32); v += __shfl_xor(v, 16); v += __shfl_xor(v, 8);
            v += __shfl_xor(v, 4);  v += __shfl_xor(v, 2);  v += __shfl_xor(v, 1);
            if (lane == 0) Hlds[t][obase + o] = v;
        }
    }
    if (wave == 0) {
#pragma unroll
        for (int t = 0; t < 8; ++t) {
            float v = accN[t];
            v += __shfl_xor(v, 32); v += __shfl_xor(v, 16); v += __shfl_xor(v, 8);
            v += __shfl_xor(v, 4);  v += __shfl_xor(v, 2);  v += __shfl_xor(v, 1);
            if (lane == 0) Hlds[t][24] = v;
        }
    }
    __syncthreads();

    // gates + sinkhorn: threads 0..127, token t = tid>>4, entry e = tid&15
    if (tid < 128) {
        const int t = tid >> 4;
        const int e = tid & 15;
        const float normsq = Hlds[t][24];
        const float inv_r  = sqrtf(8192.0f / normsq);
        const float a0 = av[0], a1 = av[1], a2 = av[2];
        float* g = gates + (t0 + t) * 24;

        float K = expf(inv_r * Hlds[t][8 + e] * a2 + bv[8 + e]);
        for (int it = 0; it < 20; ++it) {
            float rs = K + __shfl_xor(K, 1);
            rs += __shfl_xor(rs, 2);
            K = K / (rs + 1e-20f);
            float cs = K + __shfl_xor(K, 4);
            cs += __shfl_xor(cs, 8);
            K = K / (cs + 1e-20f);
        }
        g[8 + e] = K;

        if (e < 4) {
            float xp = inv_r * Hlds[t][e] * a0 + bv[e];
            g[e] = 1.0f / (1.0f + expf(-xp));
            float xq = inv_r * Hlds[t][4 + e] * a1 + bv[4 + e];
            g[4 + e] = 2.0f / (1.0f + expf(-xq));
        }
    }
}

__global__ __launch_bounds__(256)
void mhc_recombine(const float* __restrict__ hs,
                   const float* __restrict__ gates,
                   float* __restrict__ out)
{
    const long long tok = blockIdx.x;
    __shared__ float g[24];
    if (threadIdx.x < 24) g[threadIdx.x] = gates[tok * 24 + threadIdx.x];
    __syncthreads();

    float pre[4], post[4], res[16];
#pragma unroll
    for (int n = 0; n < 4; ++n) { pre[n] = g[n]; post[n] = g[4 + n]; }
#pragma unroll
    for (int e = 0; e < 16; ++e) res[e] = g[8 + e];

    const float4* h4 = reinterpret_cast<const float4*>(hs) + tok * 2048;
    float4*       o4 = reinterpret_cast<float4*>(out) + tok * 2048;

#pragma unroll
    for (int ii = 0; ii < 2; ++ii) {
        const int c4 = threadIdx.x + (ii << 8);   // 0..511 within a branch row
        float4 h[4];
#pragma unroll
        for (int n = 0; n < 4; ++n) h[n] = h4[n * 512 + c4];

        float4 hp;
        hp.x = pre[0]*h[0].x + pre[1]*h[1].x + pre[2]*h[2].x + pre[3]*h[3].x;
        hp.y = pre[0]*h[0].y + pre[1]*h[1].y + pre[2]*h[2].y + pre[3]*h[3].y;
        hp.z = pre[0]*h[0].z + pre[1]*h[1].z + pre[2]*h[2].z + pre[3]*h[3].z;
        hp.w = pre[0]*h[0].w + pre[1]*h[1].w + pre[2]*h[2].w + pre[3]*h[3].w;

#pragma unroll
        for (int m = 0; m < 4; ++m) {
            const float r0 = res[m*4+0], r1 = res[m*4+1], r2 = res[m*4+2], r3 = res[m*4+3];
            const float pm = post[m];
            float4 o;
            o.x = pm*hp.x + r0*h[0].x + r1*h[1].x + r2*h[2].x + r3*h[3].x;
            o.y = pm*hp.y + r0*h[0].y + r1*h[1].y + r2*h[2].y + r3*h[3].y;
            o.z = pm*hp.z + r0*h[0].z + r1*h[1].z + r2*h[2].z + r3*h[3].z;
            o.w = pm*hp.w + r0*h[0].w + r1*h[1].w + r2*h[2].w + r3*h[3].w;
            o4[m * 512 + c4] = o;
        }
    }
}

extern "C" void kernel_launch(void* const* d_in, const int* in_sizes, int n_in,
                              void* d_out, int out_size, void* d_ws, size_t ws_size,
                              hipStream_t stream) {
    const float* hs  = (const float*)d_in[0];   // [B, L, 4, 2048] fp32
    const float* Wp  = (const float*)d_in[1];   // [24, 8192] fp32
    const float* av  = (const float*)d_in[2];   // [3]
    const float* bv  = (const float*)d_in[3];   // [24]
    float* out   = (float*)d_out;               // [B, L, 4, 2048] fp32
    float* gates = (float*)d_ws;                // [tokens][24] = 786KB scratch

    const int tokens = in_sizes[0] / 8192;      // 8192

    mhc_gates<<<tokens / 8, 256, 0, stream>>>(hs, Wp, av, bv, gates);
    mhc_recombine<<<tokens, 256, 0, stream>>>(hs, gates, out);
}